// Round 1
// baseline (310.777 us; speedup 1.0000x reference)
//
#include <hip/hip_runtime.h>
#include <math.h>

#define NCLASS 19
#define IGNORE_LBL (-1)

// Problem shape (from reference setup_inputs): logits [8,19,512,1024] f32,
// target [8,512,1024] i32.
constexpr int BDIM   = 8;
constexpr int HWDIM  = 512 * 1024;          // 524288, class stride in logits
constexpr int NPIX   = BDIM * HWDIM;        // 4194304
constexpr double BETA = 0.999;

struct WS {
    double num;                 // sum(w_t * tgt_logp)
    double den;                 // sum(w_t)
    int    counts[NCLASS];
    float  weights[NCLASS];
};

__global__ void init_ws(WS* ws) {
    int t = threadIdx.x;
    if (t == 0) { ws->num = 0.0; ws->den = 0.0; }
    if (t < NCLASS) ws->counts[t] = 0;
}

__global__ void hist_kernel(const int* __restrict__ tgt, WS* __restrict__ ws, int n4) {
    __shared__ int sh[NCLASS];
    if (threadIdx.x < NCLASS) sh[threadIdx.x] = 0;
    __syncthreads();
    int stride = gridDim.x * blockDim.x;
    for (int i = blockIdx.x * blockDim.x + threadIdx.x; i < n4; i += stride) {
        int4 t = reinterpret_cast<const int4*>(tgt)[i];
        if (t.x >= 0 && t.x < NCLASS) atomicAdd(&sh[t.x], 1);
        if (t.y >= 0 && t.y < NCLASS) atomicAdd(&sh[t.y], 1);
        if (t.z >= 0 && t.z < NCLASS) atomicAdd(&sh[t.z], 1);
        if (t.w >= 0 && t.w < NCLASS) atomicAdd(&sh[t.w], 1);
    }
    __syncthreads();
    if (threadIdx.x < NCLASS && sh[threadIdx.x] != 0)
        atomicAdd(&ws->counts[threadIdx.x], sh[threadIdx.x]);
}

__global__ void weights_kernel(WS* ws) {
    int c = threadIdx.x;
    if (c < NCLASS) {
        double total = (double)ws->counts[c];
        float w = 0.0f;
        if (total > 0.0) {
            double p = exp(total * log(BETA));           // beta^total
            w = (float)((1.0 - BETA) / (1.0 - p));
        }
        ws->weights[c] = w;
    }
}

__global__ __launch_bounds__(256)
void loss_kernel(const float* __restrict__ logits, const int* __restrict__ tgt,
                 WS* __restrict__ ws) {
    __shared__ float  s_w[NCLASS];
    __shared__ double sh_n[4], sh_d[4];

    int tid = threadIdx.x;
    if (tid < NCLASS) s_w[tid] = ws->weights[tid];
    __syncthreads();

    long gid = (long)blockIdx.x * blockDim.x + tid;   // one float4-unit = 4 pixels
    long p   = gid * 4;
    int  b   = (int)(p / HWDIM);
    int  hw  = (int)(p % HWDIM);

    int4 t = *reinterpret_cast<const int4*>(tgt + p);
    int tcx = min(max(t.x, 0), NCLASS - 1);
    int tcy = min(max(t.y, 0), NCLASS - 1);
    int tcz = min(max(t.z, 0), NCLASS - 1);
    int tcw = min(max(t.w, 0), NCLASS - 1);

    const float4* base = reinterpret_cast<const float4*>(
        logits + (long)b * NCLASS * HWDIM + hw);
    const long cstride = HWDIM / 4;                   // class stride in float4 units

    float4 vv[NCLASS];
    float4 mx = make_float4(-INFINITY, -INFINITY, -INFINITY, -INFINITY);
    float4 tv = make_float4(0.f, 0.f, 0.f, 0.f);

#pragma unroll
    for (int c = 0; c < NCLASS; ++c) {
        float4 v = base[(long)c * cstride];
        vv[c] = v;
        mx.x = fmaxf(mx.x, v.x);
        mx.y = fmaxf(mx.y, v.y);
        mx.z = fmaxf(mx.z, v.z);
        mx.w = fmaxf(mx.w, v.w);
        if (c == tcx) tv.x = v.x;
        if (c == tcy) tv.y = v.y;
        if (c == tcz) tv.z = v.z;
        if (c == tcw) tv.w = v.w;
    }

    float4 se = make_float4(0.f, 0.f, 0.f, 0.f);
#pragma unroll
    for (int c = 0; c < NCLASS; ++c) {
        se.x += expf(vv[c].x - mx.x);
        se.y += expf(vv[c].y - mx.y);
        se.z += expf(vv[c].z - mx.z);
        se.w += expf(vv[c].w - mx.w);
    }

    // tgt_logp = tv - (mx + log(se)); weight 0 at ignored pixels
    float wtx = (t.x != IGNORE_LBL) ? s_w[tcx] : 0.f;
    float wty = (t.y != IGNORE_LBL) ? s_w[tcy] : 0.f;
    float wtz = (t.z != IGNORE_LBL) ? s_w[tcz] : 0.f;
    float wtw = (t.w != IGNORE_LBL) ? s_w[tcw] : 0.f;

    float num_p = wtx * (tv.x - (mx.x + logf(se.x)))
                + wty * (tv.y - (mx.y + logf(se.y)))
                + wtz * (tv.z - (mx.z + logf(se.z)))
                + wtw * (tv.w - (mx.w + logf(se.w)));
    float den_p = wtx + wty + wtz + wtw;

    // wave64 reduce
#pragma unroll
    for (int off = 32; off > 0; off >>= 1) {
        num_p += __shfl_down(num_p, off);
        den_p += __shfl_down(den_p, off);
    }
    int wave = tid >> 6, lane = tid & 63;
    if (lane == 0) { sh_n[wave] = (double)num_p; sh_d[wave] = (double)den_p; }
    __syncthreads();
    if (tid == 0) {
        double n = sh_n[0] + sh_n[1] + sh_n[2] + sh_n[3];
        double d = sh_d[0] + sh_d[1] + sh_d[2] + sh_d[3];
        atomicAdd(&ws->num, n);
        atomicAdd(&ws->den, d);
    }
}

__global__ void finalize_kernel(const WS* __restrict__ ws, float* __restrict__ out) {
    if (threadIdx.x == 0) {
        out[0] = (float)(-(ws->num / ws->den));
    }
}

extern "C" void kernel_launch(void* const* d_in, const int* in_sizes, int n_in,
                              void* d_out, int out_size, void* d_ws, size_t ws_size,
                              hipStream_t stream) {
    const float* logits = (const float*)d_in[0];
    const int*   target = (const int*)d_in[1];
    float*       out    = (float*)d_out;
    WS*          ws     = (WS*)d_ws;

    init_ws<<<1, 64, 0, stream>>>(ws);
    hist_kernel<<<1024, 256, 0, stream>>>(target, ws, NPIX / 4);
    weights_kernel<<<1, 32, 0, stream>>>(ws);
    loss_kernel<<<NPIX / 4 / 256, 256, 0, stream>>>(logits, target, ws);
    finalize_kernel<<<1, 1, 0, stream>>>(ws, out);
}

// Round 2
// 145.108 us; speedup vs baseline: 2.1417x; 2.1417x over previous
//
#include <hip/hip_runtime.h>
#include <math.h>

#define NCLASS 19
#define IGNORE_LBL (-1)

// Problem shape: logits [8,19,512,1024] f32, target [8,512,1024] i32.
constexpr int BDIM   = 8;
constexpr int HWDIM  = 512 * 1024;          // 524288, class stride in logits
constexpr int NPIX   = BDIM * HWDIM;        // 4194304
constexpr double BETA = 0.999;

struct WS {
    double num;                 // sum(w_t * tgt_logp)
    double den;                 // sum(w_t)
    int    counts[NCLASS];
    float  weights[NCLASS];
};

__global__ void init_ws(WS* ws) {
    int t = threadIdx.x;
    if (t == 0) { ws->num = 0.0; ws->den = 0.0; }
    if (t < NCLASS) ws->counts[t] = 0;
}

__global__ void hist_kernel(const int* __restrict__ tgt, WS* __restrict__ ws, int n4) {
    __shared__ int sh[NCLASS];
    if (threadIdx.x < NCLASS) sh[threadIdx.x] = 0;
    __syncthreads();
    int stride = gridDim.x * blockDim.x;
    for (int i = blockIdx.x * blockDim.x + threadIdx.x; i < n4; i += stride) {
        int4 t = reinterpret_cast<const int4*>(tgt)[i];
        if (t.x >= 0 && t.x < NCLASS) atomicAdd(&sh[t.x], 1);
        if (t.y >= 0 && t.y < NCLASS) atomicAdd(&sh[t.y], 1);
        if (t.z >= 0 && t.z < NCLASS) atomicAdd(&sh[t.z], 1);
        if (t.w >= 0 && t.w < NCLASS) atomicAdd(&sh[t.w], 1);
    }
    __syncthreads();
    if (threadIdx.x < NCLASS && sh[threadIdx.x] != 0)
        atomicAdd(&ws->counts[threadIdx.x], sh[threadIdx.x]);
}

__global__ void weights_kernel(WS* ws) {
    int c = threadIdx.x;
    if (c < NCLASS) {
        double total = (double)ws->counts[c];
        float w = 0.0f;
        if (total > 0.0) {
            double p = exp(total * log(BETA));           // beta^total
            w = (float)((1.0 - BETA) / (1.0 - p));
        }
        ws->weights[c] = w;
    }
}

// Online-softmax per pixel: no per-thread class array -> no scratch spill.
// Each thread handles 8 consecutive pixels (2 float4 units) for MLP.
__global__ __launch_bounds__(256)
void loss_kernel(const float* __restrict__ logits, const int* __restrict__ tgt,
                 WS* __restrict__ ws) {
    __shared__ float  s_w[NCLASS];
    __shared__ double sh_n[4], sh_d[4];

    int tid = threadIdx.x;
    if (tid < NCLASS) s_w[tid] = ws->weights[tid];
    __syncthreads();

    long gid = (long)blockIdx.x * blockDim.x + tid;   // one unit = 8 pixels
    long p   = gid * 8;
    int  b   = (int)(p / HWDIM);
    int  hw  = (int)(p % HWDIM);

    int4 t0 = *reinterpret_cast<const int4*>(tgt + p);
    int4 t1 = *reinterpret_cast<const int4*>(tgt + p + 4);

    const float* base = logits + (long)b * NCLASS * HWDIM + hw;

    // running max m, running sum s, target logit tv — per pixel, scalars only
    float ma0 = -INFINITY, ma1 = -INFINITY, ma2 = -INFINITY, ma3 = -INFINITY;
    float mb0 = -INFINITY, mb1 = -INFINITY, mb2 = -INFINITY, mb3 = -INFINITY;
    float sa0 = 0.f, sa1 = 0.f, sa2 = 0.f, sa3 = 0.f;
    float sb0 = 0.f, sb1 = 0.f, sb2 = 0.f, sb3 = 0.f;
    float ta0 = 0.f, ta1 = 0.f, ta2 = 0.f, ta3 = 0.f;
    float tb0 = 0.f, tb1 = 0.f, tb2 = 0.f, tb3 = 0.f;

    float4 va = *reinterpret_cast<const float4*>(base);
    float4 vb = *reinterpret_cast<const float4*>(base + 4);

#pragma unroll
    for (int c = 0; c < NCLASS; ++c) {
        float4 na, nb;
        if (c < NCLASS - 1) {
            na = *reinterpret_cast<const float4*>(base + (long)(c + 1) * HWDIM);
            nb = *reinterpret_cast<const float4*>(base + (long)(c + 1) * HWDIM + 4);
        }
        // ---- process unit A ----
        {
            float nm;
            nm = fmaxf(ma0, va.x); sa0 = sa0 * __expf(ma0 - nm) + __expf(va.x - nm); ma0 = nm;
            nm = fmaxf(ma1, va.y); sa1 = sa1 * __expf(ma1 - nm) + __expf(va.y - nm); ma1 = nm;
            nm = fmaxf(ma2, va.z); sa2 = sa2 * __expf(ma2 - nm) + __expf(va.z - nm); ma2 = nm;
            nm = fmaxf(ma3, va.w); sa3 = sa3 * __expf(ma3 - nm) + __expf(va.w - nm); ma3 = nm;
            if (c == t0.x) ta0 = va.x;
            if (c == t0.y) ta1 = va.y;
            if (c == t0.z) ta2 = va.z;
            if (c == t0.w) ta3 = va.w;
        }
        // ---- process unit B ----
        {
            float nm;
            nm = fmaxf(mb0, vb.x); sb0 = sb0 * __expf(mb0 - nm) + __expf(vb.x - nm); mb0 = nm;
            nm = fmaxf(mb1, vb.y); sb1 = sb1 * __expf(mb1 - nm) + __expf(vb.y - nm); mb1 = nm;
            nm = fmaxf(mb2, vb.z); sb2 = sb2 * __expf(mb2 - nm) + __expf(vb.z - nm); mb2 = nm;
            nm = fmaxf(mb3, vb.w); sb3 = sb3 * __expf(mb3 - nm) + __expf(vb.w - nm); mb3 = nm;
            if (c == t1.x) tb0 = vb.x;
            if (c == t1.y) tb1 = vb.y;
            if (c == t1.z) tb2 = vb.z;
            if (c == t1.w) tb3 = vb.w;
        }
        va = na; vb = nb;
    }

    // weights; 0 at ignored pixels (target==-1 never matched a class, tv=0, but
    // weight 0 kills the term)
    int tc;
    float w;
    float num_p = 0.f, den_p = 0.f;

    tc = min(max(t0.x, 0), NCLASS - 1); w = (t0.x != IGNORE_LBL) ? s_w[tc] : 0.f;
    num_p += w * (ta0 - (ma0 + __logf(sa0))); den_p += w;
    tc = min(max(t0.y, 0), NCLASS - 1); w = (t0.y != IGNORE_LBL) ? s_w[tc] : 0.f;
    num_p += w * (ta1 - (ma1 + __logf(sa1))); den_p += w;
    tc = min(max(t0.z, 0), NCLASS - 1); w = (t0.z != IGNORE_LBL) ? s_w[tc] : 0.f;
    num_p += w * (ta2 - (ma2 + __logf(sa2))); den_p += w;
    tc = min(max(t0.w, 0), NCLASS - 1); w = (t0.w != IGNORE_LBL) ? s_w[tc] : 0.f;
    num_p += w * (ta3 - (ma3 + __logf(sa3))); den_p += w;

    tc = min(max(t1.x, 0), NCLASS - 1); w = (t1.x != IGNORE_LBL) ? s_w[tc] : 0.f;
    num_p += w * (tb0 - (mb0 + __logf(sb0))); den_p += w;
    tc = min(max(t1.y, 0), NCLASS - 1); w = (t1.y != IGNORE_LBL) ? s_w[tc] : 0.f;
    num_p += w * (tb1 - (mb1 + __logf(sb1))); den_p += w;
    tc = min(max(t1.z, 0), NCLASS - 1); w = (t1.z != IGNORE_LBL) ? s_w[tc] : 0.f;
    num_p += w * (tb2 - (mb2 + __logf(sb2))); den_p += w;
    tc = min(max(t1.w, 0), NCLASS - 1); w = (t1.w != IGNORE_LBL) ? s_w[tc] : 0.f;
    num_p += w * (tb3 - (mb3 + __logf(sb3))); den_p += w;

    // wave64 reduce
#pragma unroll
    for (int off = 32; off > 0; off >>= 1) {
        num_p += __shfl_down(num_p, off);
        den_p += __shfl_down(den_p, off);
    }
    int wave = tid >> 6, lane = tid & 63;
    if (lane == 0) { sh_n[wave] = (double)num_p; sh_d[wave] = (double)den_p; }
    __syncthreads();
    if (tid == 0) {
        double n = sh_n[0] + sh_n[1] + sh_n[2] + sh_n[3];
        double d = sh_d[0] + sh_d[1] + sh_d[2] + sh_d[3];
        atomicAdd(&ws->num, n);
        atomicAdd(&ws->den, d);
    }
}

__global__ void finalize_kernel(const WS* __restrict__ ws, float* __restrict__ out) {
    if (threadIdx.x == 0) {
        out[0] = (float)(-(ws->num / ws->den));
    }
}

extern "C" void kernel_launch(void* const* d_in, const int* in_sizes, int n_in,
                              void* d_out, int out_size, void* d_ws, size_t ws_size,
                              hipStream_t stream) {
    const float* logits = (const float*)d_in[0];
    const int*   target = (const int*)d_in[1];
    float*       out    = (float*)d_out;
    WS*          ws     = (WS*)d_ws;

    init_ws<<<1, 64, 0, stream>>>(ws);
    hist_kernel<<<1024, 256, 0, stream>>>(target, ws, NPIX / 4);
    weights_kernel<<<1, 32, 0, stream>>>(ws);
    loss_kernel<<<NPIX / 8 / 256, 256, 0, stream>>>(logits, target, ws);
    finalize_kernel<<<1, 1, 0, stream>>>(ws, out);
}